// Round 4
// baseline (171.952 us; speedup 1.0000x reference)
//
#include <hip/hip_runtime.h>
#include <stdint.h>
#include <math.h>

// RpnLoss: BATCH=4096 samples, A = 5*17*17 = 1445 anchors.
// R4: one wave per sample (4 waves/block, grid N/4), zero barriers.
// vs R3 (which SPILLED: VGPR=48, rn[23]+cv[23] arrays went to scratch):
//  - per-anchor (r<<2)|enc lives in per-wave LDS (5.8 KB/wave), not registers
//  - selected cls values reloaded from L2 in pass 2 (~50/sample, cheap)
//  - ballot+popcount compaction instead of LDS counter atomics (no ds_add_rtn)
//  - amdgpu_waves_per_eu(4,4): grid supplies only 4 waves/EU, so give the
//    allocator the full 128-VGPR budget -> no spill, deep load pipelining
// PRNG (bit-exact, verified R1-R3): key_i = threefry((0,42),(0,i));
// kpos[n]=key_n, kneg[n]=key_{N+n}; draw j: r = (o0^o1 of threefry(key,(0,j)))>>9.

#define A_TOT 1445
#define NITER 23        // ceil(1445/64)
#define WPB 4           // waves (=samples) per block
#define POS_MAX 64      // geometric bound on n_pos is ~10-40; R3 passed with 64
#define CAND_MAX 128    // boundary-bin load ~ Poisson(5.6); 128 is >>6 sigma

__device__ __forceinline__ void tf2x32(uint32_t k0, uint32_t k1, uint32_t x0, uint32_t x1,
                                       uint32_t& o0, uint32_t& o1)
{
  const uint32_t k2 = k0 ^ k1 ^ 0x1BD11BDAu;
  x0 += k0; x1 += k1;
#define TFR(r) { x0 += x1; x1 = __builtin_rotateleft32(x1, (r)); x1 ^= x0; }
  TFR(13) TFR(15) TFR(26) TFR(6)
  x0 += k1; x1 += k2 + 1u;
  TFR(17) TFR(29) TFR(16) TFR(24)
  x0 += k2; x1 += k0 + 2u;
  TFR(13) TFR(15) TFR(26) TFR(6)
  x0 += k0; x1 += k1 + 3u;
  TFR(17) TFR(29) TFR(16) TFR(24)
  x0 += k1; x1 += k2 + 4u;
  TFR(13) TFR(15) TFR(26) TFR(6)
  x0 += k2; x1 += k0 + 5u;
#undef TFR
  o0 = x0; o1 = x1;
}

// logaddexp(0,x) via HW exp/log; rel err ~2^-21 << 3e-2 threshold (passed R1-R3).
__device__ __forceinline__ float lae0(float x){
  return fmaxf(x, 0.0f) + __logf(1.0f + __expf(-fabsf(x)));
}

__global__ void __attribute__((amdgpu_waves_per_eu(4, 4)))
__launch_bounds__(WPB * 64) rpn_loss_kernel(
    const float* __restrict__ pred_cls, const float* __restrict__ pred_reg,
    const float* __restrict__ gt_bbox, const float* __restrict__ anchor_center,
    const float* __restrict__ anchor_corner,
    float* __restrict__ part,   // [3][N] partials: lc, lr, acc
    int N)
{
  __shared__ uint32_t s_rnm[WPB][A_TOT];     // (r<<2)|enc  enc: 2=pos 1=ignore 0=neg
  __shared__ uint32_t s_hist[WPB][256];
  __shared__ uint32_t s_pidx[WPB][POS_MAX];
  __shared__ float    s_pcls[WPB][POS_MAX];
  __shared__ uint32_t s_cand[WPB][CAND_MAX];
  // total: 4 * (5780 + 1024 + 256 + 256 + 512) = ~31.3 KB -> >=5 blocks/CU cap,
  // grid supplies 4/CU, so LDS is not the limiter.

  const int w    = threadIdx.x >> 6;
  const int lane = threadIdx.x & 63;
  const int n    = blockIdx.x * WPB + w;
  const uint64_t lmask_lt = (1ull << lane) - 1ull;

  // zero per-wave histogram (same-wave DS ordering; no barrier needed)
  #pragma unroll
  for (int b = 0; b < 4; b++) s_hist[w][lane * 4 + b] = 0u;

  const float g0 = gt_bbox[4 * n + 0];
  const float g1 = gt_bbox[4 * n + 1];
  const float g2 = gt_bbox[4 * n + 2];
  const float g3 = gt_bbox[4 * n + 3];
  const float area_a = (g2 - g0) * (g3 - g1);

  uint32_t kp0, kp1, kn0, kn1;
  tf2x32(0u, 42u, 0u, (uint32_t)n,       kp0, kp1);
  tf2x32(0u, 42u, 0u, (uint32_t)(N + n), kn0, kn1);

  const float*  cls_base = pred_cls + (size_t)n * A_TOT;
  const float4* cornv = (const float4*)anchor_corner;

  uint32_t posCnt = 0u, negCnt = 0u;
  float accc = 0.0f;

  // ---- Phase A: IoU + neg-key hash -> LDS + histogram + pos compaction + accuracy
  #pragma unroll
  for (int t = 0; t < NITER; t++){
    int j = lane + 64 * t;
    bool valid = (j < A_TOT);            // only t==22 partially valid (lane<37)
    int jc = valid ? j : (A_TOT - 1);
    float4 cr = cornv[jc];
    float c = cls_base[jc];
    float ltx = fmaxf(g0, cr.x), lty = fmaxf(g1, cr.y);
    float rbx = fminf(g2, cr.z), rby = fminf(g3, cr.w);
    float inter = fmaxf(rbx - ltx, 0.0f) * fmaxf(rby - lty, 0.0f);
    float area_b = (cr.z - cr.x) * (cr.w - cr.y);
    float iou = inter / (area_a + area_b - inter);
    bool pos = valid && (iou > 0.6f);
    bool neg = valid && (iou < 0.3f);
    uint32_t o0, o1;
    tf2x32(kn0, kn1, 0u, (uint32_t)j, o0, o1);
    uint32_t r = (o0 ^ o1) >> 9;         // 23-bit rank value
    uint32_t enc = pos ? 2u : (neg ? 0u : 1u);
    if (valid) s_rnm[w][j] = (r << 2) | enc;
    if (neg)   atomicAdd(&s_hist[w][r >> 15], 1u);
    uint64_t pm = __ballot(pos);
    if (pos){
      uint32_t id = posCnt + (uint32_t)__popcll(pm & lmask_lt);
      if (id < POS_MAX){ s_pidx[w][id] = (uint32_t)j; s_pcls[w][id] = c; }
    }
    posCnt += (uint32_t)__popcll(pm);
    negCnt += (uint32_t)__popcll(__ballot(neg));
    accc += (valid && ((c >= 0.6f) == pos)) ? 1.0f : 0.0f;
  }
  // same-wave LDS ops are ordered; no barrier anywhere.

  const int n_pos = min((int)posCnt, POS_MAX);
  const int n_neg = (int)negCnt;
  const int k_p = min(n_pos, 16);
  const int k_n = min(n_neg, (n_pos > 0) ? 3 * n_pos : 48);

  // ---- inclusive scan of 256-bin histogram (4 bins/lane + wave shuffle scan)
  uint32_t S0, S1, S2, S3;
  {
    int b = lane * 4;
    uint32_t v0 = s_hist[w][b], v1 = s_hist[w][b+1], v2 = s_hist[w][b+2], v3 = s_hist[w][b+3];
    S0 = v0; S1 = S0 + v1; S2 = S1 + v2; S3 = S2 + v3;
    uint32_t x = S3;
    #pragma unroll
    for (int off = 1; off < 64; off <<= 1){
      uint32_t tmp = __shfl_up(x, off, 64);
      if (lane >= off) x += tmp;
    }
    uint32_t excl = x - S3;
    S0 += excl; S1 += excl; S2 += excl; S3 += excl;
    s_hist[w][b] = S0; s_hist[w][b+1] = S1; s_hist[w][b+2] = S2; s_hist[w][b+3] = S3;
  }

  // ---- boundary bin Bb = first bin with cumsum >= k_n; m = take-from-Bb count
  int Bb = 256, m = 0;
  if (k_n > 0){
    unsigned long long bal = __ballot(S3 >= (uint32_t)k_n);
    int fl = __ffsll(bal) - 1;           // exists: lane63 S3 = n_neg >= k_n
    uint32_t t0 = __shfl(S0, fl, 64), t1 = __shfl(S1, fl, 64), t2 = __shfl(S2, fl, 64);
    int sub = (t0 >= (uint32_t)k_n) ? 0 : ((t1 >= (uint32_t)k_n) ? 1 : ((t2 >= (uint32_t)k_n) ? 2 : 3));
    Bb = fl * 4 + sub;
    uint32_t before = (Bb == 0) ? 0u : s_hist[w][Bb - 1];
    m = k_n - (int)before;
  }

  // ---- positives: pos-key hash (one/lane), shuffle ranking, bce + reg loss
  float lc = 0.0f, lr = 0.0f;
  if (n_pos > 0){
    uint32_t myr = 0u, myj = 0u; float myc = 0.0f;
    if (lane < n_pos){
      myj = s_pidx[w][lane];
      myc = s_pcls[w][lane];
      uint32_t o0, o1;
      tf2x32(kp0, kp1, 0u, myj, o0, o1);
      myr = (o0 ^ o1) >> 9;
    }
    int rank = 0;
    for (int l = 0; l < n_pos; l++){
      uint32_t r2 = __shfl(myr, l, 64), j2 = __shfl(myj, l, 64);
      if (lane < n_pos && (r2 < myr || (r2 == myr && j2 < myj))) rank++;
    }
    if (lane < n_pos){
      if (rank < k_p) lc += lae0(-myc);
      float gcx = (g0 + g2) * 0.5f, gcy = (g1 + g3) * 0.5f;
      float gw = g2 - g0, gh = g3 - g1;
      float4 ce = ((const float4*)anchor_center)[myj];
      const float* reg_base = pred_reg + (size_t)n * 4 * A_TOT;
      float t0 = (gcx - ce.x) / ce.z;
      float t1 = (gcy - ce.y) / ce.w;
      float t2 = __logf(gw / ce.z);
      float t3 = __logf(gh / ce.w);
      float d0 = reg_base[myj]             - t0;
      float d1 = reg_base[A_TOT + myj]     - t1;
      float d2 = reg_base[2 * A_TOT + myj] - t2;
      float d3 = reg_base[3 * A_TOT + myj] - t3;
      lr = d0 * d0 + d1 * d1 + d2 * d2 + d3 * d3;
    }
  }

  // ---- negatives: re-read LDS words, bce for bin<Bb, compact bin==Bb candidates
  if (k_n > 0){
    uint32_t candCnt = 0u;
    #pragma unroll
    for (int t = 0; t < NITER; t++){
      int j = lane + 64 * t;
      bool valid = (j < A_TOT);
      uint32_t word = valid ? s_rnm[w][j] : 1u;   // enc=1 -> ignored
      bool isneg = (word & 3u) == 0u;
      int bin = (int)(word >> 17);
      if (isneg && bin < Bb) lc += lae0(cls_base[j]);   // L2-hot reload
      bool inB = isneg && (bin == Bb);
      uint64_t bm = __ballot(inB);
      if (inB){
        uint32_t id = candCnt + (uint32_t)__popcll(bm & lmask_lt);
        if (id < CAND_MAX)
          s_cand[w][id] = (((word >> 2) & 0x7FFFu) << 11) | (uint32_t)j;
      }
      candCnt += (uint32_t)__popcll(bm);
    }
    const int L = min((int)candCnt, CAND_MAX);
    for (int c2 = lane; c2 < L; c2 += 64){
      uint32_t my = s_cand[w][c2];
      int rank = 0;
      for (int l = 0; l < L; l++) rank += (s_cand[w][l] < my) ? 1 : 0;  // broadcast
      if (rank < m) lc += lae0(cls_base[my & 0x7FFu]);
    }
  }

  // ---- wave reduce 3 floats, lane 0 writes partials
  float v0 = lc, v1 = lr, v2 = accc;
  #pragma unroll
  for (int off = 32; off > 0; off >>= 1){
    v0 += __shfl_down(v0, off, 64);
    v1 += __shfl_down(v1, off, 64);
    v2 += __shfl_down(v2, off, 64);
  }
  if (lane == 0){
    int denom = k_p + k_n; if (denom < 1) denom = 1;
    part[n]         = v0 / (float)denom;
    part[N + n]     = (n_pos > 0) ? (v1 / (4.0f * (float)n_pos)) : 0.0f;
    part[2 * N + n] = v2 * (1.0f / (float)A_TOT);
  }
}

__global__ void __launch_bounds__(256) reduce_kernel(const float* __restrict__ part,
                                                     float* __restrict__ out, int N)
{
  const int tid = threadIdx.x;
  float lc = 0.0f, lr = 0.0f, ac = 0.0f;
  for (int i = tid; i < N; i += 256){
    lc += part[i];
    lr += part[N + i];
    ac += part[2 * N + i];
  }
  __shared__ float s[12];
  #pragma unroll
  for (int off = 32; off > 0; off >>= 1){
    lc += __shfl_down(lc, off, 64);
    lr += __shfl_down(lr, off, 64);
    ac += __shfl_down(ac, off, 64);
  }
  const int wave = tid >> 6, lane = tid & 63;
  if (lane == 0){ s[wave] = lc; s[4 + wave] = lr; s[8 + wave] = ac; }
  __syncthreads();
  if (tid == 0){
    float LC = s[0] + s[1] + s[2] + s[3];
    float LR = s[4] + s[5] + s[6] + s[7];
    float AC = s[8] + s[9] + s[10] + s[11];
    float inv = 1.0f / (float)N;
    LC *= inv; LR *= inv; AC *= inv;
    out[0] = LC + LR;
    out[1] = LC;
    out[2] = LR;
    out[3] = AC;
  }
}

extern "C" void kernel_launch(void* const* d_in, const int* in_sizes, int n_in,
                              void* d_out, int out_size, void* d_ws, size_t ws_size,
                              hipStream_t stream)
{
  const float* pred_cls = (const float*)d_in[0];
  const float* pred_reg = (const float*)d_in[1];
  const float* gt_bbox  = (const float*)d_in[2];
  const float* a_center = (const float*)d_in[3];
  const float* a_corner = (const float*)d_in[4];
  float* part = (float*)d_ws;            // 3*N floats
  float* out  = (float*)d_out;

  const int N = in_sizes[2] / 4;         // 4096

  hipLaunchKernelGGL(rpn_loss_kernel, dim3(N / WPB), dim3(WPB * 64), 0, stream,
                     pred_cls, pred_reg, gt_bbox, a_center, a_corner, part, N);
  hipLaunchKernelGGL(reduce_kernel, dim3(1), dim3(256), 0, stream, part, out, N);
}